// Round 1
// baseline (1234.325 us; speedup 1.0000x reference)
//
#include <hip/hip_runtime.h>
#include <math.h>

#define BZ   8
#define DDIM 128
#define NN   2048
#define KSEL 30
#define KEEP 1024

// ---------- block reductions (blockDim == 256) ----------
__device__ __forceinline__ double blockReduceD(double x, double* lds) {
  #pragma unroll
  for (int off = 32; off; off >>= 1) x += __shfl_down(x, off, 64);
  int wv = threadIdx.x >> 6;
  __syncthreads();
  if ((threadIdx.x & 63) == 0) lds[wv] = x;
  __syncthreads();
  return lds[0] + lds[1] + lds[2] + lds[3];
}

__device__ __forceinline__ int blockReduceI(int x, int* lds) {
  #pragma unroll
  for (int off = 32; off; off >>= 1) x += __shfl_down(x, off, 64);
  int wv = threadIdx.x >> 6;
  __syncthreads();
  if ((threadIdx.x & 63) == 0) lds[wv] = x;
  __syncthreads();
  return lds[0] + lds[1] + lds[2] + lds[3];
}

// ---------- K1: per-(b,feature) mean/std(ddof=1) + normalize ----------
// grid 1024 (b*128+d), block 256. data layout [b][d][n] already matches XnT.
__global__ __launch_bounds__(256) void k_norm(const float* __restrict__ data,
                                              float* __restrict__ xnT) {
  __shared__ double lds[4];
  __shared__ float msd[2];
  const int blk = blockIdx.x;
  const int t = threadIdx.x;
  const float* src = data + (size_t)blk * NN;
  float* dst = xnT + (size_t)blk * NN;
  float v[8];
  double s = 0.0, s2 = 0.0;
  #pragma unroll
  for (int q = 0; q < 8; ++q) {
    v[q] = src[t + q * 256];
    double d = (double)v[q];
    s += d;
    s2 = fma(d, d, s2);
  }
  s  = blockReduceD(s, lds);
  s2 = blockReduceD(s2, lds);
  if (t == 0) {
    double mean = s * (1.0 / 2048.0);
    double var = (s2 - s * mean) / 2047.0;
    if (var < 0.0) var = 0.0;
    msd[0] = (float)mean;
    msd[1] = (float)sqrt(var);
  }
  __syncthreads();
  const float mean = msd[0];
  const float den = msd[1] + 1e-6f;
  #pragma unroll
  for (int q = 0; q < 8; ++q)
    dst[t + q * 256] = (v[q] - mean) / den;
}

// ---------- K2: sq[b][n] = sum_d Xn^2 (fp64) ----------
// grid 64, block 256 -> one thread per (b,n)
__global__ __launch_bounds__(256) void k_sq(const float* __restrict__ xnT,
                                            double* __restrict__ sq) {
  const int g = blockIdx.x * 256 + threadIdx.x;
  const int b = g >> 11, n = g & 2047;
  const float* X = xnT + (size_t)b * DDIM * NN + n;
  double s = 0.0;
  for (int d = 0; d < DDIM; ++d) {
    double x = (double)X[(size_t)d * NN];
    s = fma(x, x, s);
  }
  sq[g] = s;
}

// ---------- shared distance-row computation (identical in K3 & K5) ----------
// thread t owns columns j = t*8 .. t*8+7; returns fp32-rounded distances
__device__ __forceinline__ void dist8(const float* __restrict__ Xb,
                                      const float* row, double sqi,
                                      const double* __restrict__ sqb,
                                      int t, float f[8]) {
  double acc[8];
  #pragma unroll
  for (int q = 0; q < 8; ++q) acc[q] = 0.0;
  for (int d = 0; d < DDIM; ++d) {
    const double r = (double)row[d];
    const float4* c4 = (const float4*)(Xb + ((size_t)d << 11)) + (t << 1);
    const float4 c0 = c4[0], c1 = c4[1];
    acc[0] = fma(r, (double)c0.x, acc[0]);
    acc[1] = fma(r, (double)c0.y, acc[1]);
    acc[2] = fma(r, (double)c0.z, acc[2]);
    acc[3] = fma(r, (double)c0.w, acc[3]);
    acc[4] = fma(r, (double)c1.x, acc[4]);
    acc[5] = fma(r, (double)c1.y, acc[5]);
    acc[6] = fma(r, (double)c1.z, acc[6]);
    acc[7] = fma(r, (double)c1.w, acc[7]);
  }
  #pragma unroll
  for (int q = 0; q < 8; ++q) {
    const int j = (t << 3) + q;
    double d2 = (sqi + sqb[j]) - 2.0 * acc[q];
    if (d2 < 0.0) d2 = 0.0;
    f[q] = (float)sqrt(d2);
  }
}

// ---------- K3: per-row K-th smallest distance via radix select ----------
// grid 16384 (b*2048+i), block 256
__global__ __launch_bounds__(256) void k_select(const float* __restrict__ xnT,
                                                const double* __restrict__ sq,
                                                float* __restrict__ kth) {
  __shared__ float row[DDIM];
  __shared__ int ldsI[4];
  const int b = blockIdx.x >> 11, i = blockIdx.x & 2047;
  const int t = threadIdx.x;
  const float* Xb = xnT + (size_t)b * DDIM * NN;
  if (t < DDIM) row[t] = Xb[(size_t)t * NN + i];
  __syncthreads();
  const double* sqb = sq + (b << 11);
  const double sqi = sqb[i];
  float f[8];
  dist8(Xb, row, sqi, sqb, t, f);
  unsigned u[8];
  #pragma unroll
  for (int q = 0; q < 8; ++q) u[q] = __float_as_uint(f[q]);
  // radix select rank KSEL (0-indexed) over non-negative float bits
  unsigned pref = 0;
  int want = KSEL;
  for (int bit = 30; bit >= 0; --bit) {
    const unsigned ps = pref >> bit;  // candidate prefix with this bit = 0
    int c = 0;
    #pragma unroll
    for (int q = 0; q < 8; ++q) c += ((u[q] >> bit) == ps);
    const int tot = blockReduceI(c, ldsI);
    if (want >= tot) { want -= tot; pref |= (1u << bit); }
  }
  if (t == 0) kth[blockIdx.x] = __uint_as_float(pref);
}

// ---------- K4/K6: mean of 2048 floats -> float ----------
// grid 8, block 256
__global__ __launch_bounds__(256) void k_mean2048(const float* __restrict__ in,
                                                  float* __restrict__ out) {
  __shared__ double lds[4];
  const int b = blockIdx.x, t = threadIdx.x;
  const float* p = in + (b << 11);
  double s = 0.0;
  #pragma unroll
  for (int q = 0; q < 8; ++q) s += (double)p[t + q * 256];
  s = blockReduceD(s, lds);
  if (t == 0) out[b] = (float)(s * (1.0 / 2048.0));
}

// ---------- K5: counts vs R (recompute identical distances) ----------
// grid 16384, block 256
__global__ __launch_bounds__(256) void k_count(const float* __restrict__ xnT,
                                               const double* __restrict__ sq,
                                               const float* __restrict__ adj,
                                               const float* __restrict__ Rf,
                                               float* __restrict__ samples,
                                               float* __restrict__ neigh,
                                               float* __restrict__ degree) {
  __shared__ float row[DDIM];
  __shared__ int ldsI[4];
  const int b = blockIdx.x >> 11, i = blockIdx.x & 2047;
  const int t = threadIdx.x;
  const float* Xb = xnT + (size_t)b * DDIM * NN;
  if (t < DDIM) row[t] = Xb[(size_t)t * NN + i];
  __syncthreads();
  const double* sqb = sq + (b << 11);
  const double sqi = sqb[i];
  float f[8];
  dist8(Xb, row, sqi, sqb, t, f);
  const float R = Rf[b];
  const float* arow = adj + (size_t)i * NN + (t << 3);
  int sN = 0, nN = 0, dc = 0;
  #pragma unroll
  for (int q = 0; q < 8; ++q) {
    const float a = arow[q];
    sN += (f[q] < R) ? 1 : 0;
    // reference: adj_distance = dist*adj; zeros -> 1e10; count < R
    nN += ((a != 0.0f) && (f[q] != 0.0f) && (f[q] < R)) ? 1 : 0;
    dc += (a != 0.0f) ? 1 : 0;
  }
  sN = blockReduceI(sN, ldsI);
  nN = blockReduceI(nN, ldsI);
  dc = blockReduceI(dc, ldsI);
  if (t == 0) {
    samples[blockIdx.x] = (float)sN;
    neigh[blockIdx.x] = (float)nN;
    if (b == 0) degree[i] = (float)dc;
  }
}

// ---------- K7a: total_score (exact fp32 op order as reference) ----------
// grid 64, block 256
__global__ __launch_bounds__(256) void k_score(const float* __restrict__ neigh,
                                               const float* __restrict__ samples,
                                               const float* __restrict__ degree,
                                               const float* __restrict__ mf,
                                               float* __restrict__ score) {
  const int g = blockIdx.x * 256 + threadIdx.x;
  const int b = g >> 11, i = g & 2047;
  const float sp = neigh[g] / degree[i];
  const float s = samples[g];
  const float tp = s / (s + mf[b]);
  score[g] = (2.0f - sp) - tp;
}

// ---------- K7b: stable rank + mask ----------
// grid 64 (8 batches x 8 chunks), block 256
__global__ __launch_bounds__(256) void k_rank(const float* __restrict__ score,
                                              float* __restrict__ mask) {
  __shared__ float sc[NN];
  const int b = blockIdx.x >> 3, chunk = blockIdx.x & 7, t = threadIdx.x;
  const float* srow = score + (b << 11);
  #pragma unroll
  for (int q = 0; q < 8; ++q) sc[t + q * 256] = srow[t + q * 256];
  __syncthreads();
  const int i = chunk * 256 + t;
  const float si = sc[i];
  int less = 0, eqb = 0;
  for (int j = 0; j < NN; ++j) {
    const float sj = sc[j];
    less += (sj < si) ? 1 : 0;
    eqb += ((sj == si) && (j < i)) ? 1 : 0;
  }
  const int rank = less + eqb;
  mask[(b << 11) + i] = (rank < KEEP) ? 1.0f : 0.0f;
}

// ---------- K8: out = data * mask ----------
// grid 2048, block 256, float4 per thread
__global__ __launch_bounds__(256) void k_apply(const float* __restrict__ data,
                                               const float* __restrict__ mask,
                                               float* __restrict__ out) {
  const int g = blockIdx.x * 256 + threadIdx.x;
  const float4 d = ((const float4*)data)[g];
  const int idx = g << 2;
  const int b = idx >> 18;       // 16*8*2048 = 262144 per batch
  const int w = idx & 2047;
  const float4 mk = *(const float4*)(mask + (b << 11) + w);
  float4 o;
  o.x = d.x * mk.x; o.y = d.y * mk.y; o.z = d.z * mk.z; o.w = d.w * mk.w;
  ((float4*)out)[g] = o;
}

extern "C" void kernel_launch(void* const* d_in, const int* in_sizes, int n_in,
                              void* d_out, int out_size, void* d_ws, size_t ws_size,
                              hipStream_t stream) {
  (void)in_sizes; (void)n_in; (void)out_size; (void)ws_size;
  const float* data = (const float*)d_in[0];
  const float* adj  = (const float*)d_in[1];
  float* out = (float*)d_out;

  // XnT staged in the output buffer's first 8 MB (overwritten last by k_apply)
  float* xnT   = out;
  float* score = out + 2097152;  // total_score output slot (8*2048)

  uint8_t* w = (uint8_t*)d_ws;
  double* sq      = (double*)(w);            // 131072 B
  float*  kth     = (float*)(w + 131072);    // 65536 B
  float*  Rf      = (float*)(w + 196608);    // 32 B
  float*  samples = (float*)(w + 196672);    // 65536 B
  float*  neigh   = (float*)(w + 262208);    // 65536 B
  float*  mf      = (float*)(w + 327744);    // 32 B
  float*  degree  = (float*)(w + 327808);    // 8192 B
  float*  mask    = (float*)(w + 336000);    // 65536 B

  k_norm  <<<1024, 256, 0, stream>>>(data, xnT);
  k_sq    <<<64,   256, 0, stream>>>(xnT, sq);
  k_select<<<16384,256, 0, stream>>>(xnT, sq, kth);
  k_mean2048<<<8,  256, 0, stream>>>(kth, Rf);
  k_count <<<16384,256, 0, stream>>>(xnT, sq, adj, Rf, samples, neigh, degree);
  k_mean2048<<<8,  256, 0, stream>>>(samples, mf);
  k_score <<<64,   256, 0, stream>>>(neigh, samples, degree, mf, score);
  k_rank  <<<64,   256, 0, stream>>>(score, mask);
  k_apply <<<2048, 256, 0, stream>>>(data, mask, out);
}

// Round 2
// 464.206 us; speedup vs baseline: 2.6590x; 2.6590x over previous
//
#include <hip/hip_runtime.h>
#include <math.h>

#define BZ   8
#define DDIM 128
#define NN   2048
#define KSEL 30
#define KEEP 1024
#define ROWS 8

// ---------- block reductions (blockDim == 256) ----------
__device__ __forceinline__ double blockReduceD(double x, double* lds) {
  #pragma unroll
  for (int off = 32; off; off >>= 1) x += __shfl_down(x, off, 64);
  int wv = threadIdx.x >> 6;
  __syncthreads();
  if ((threadIdx.x & 63) == 0) lds[wv] = x;
  __syncthreads();
  return lds[0] + lds[1] + lds[2] + lds[3];
}

__device__ __forceinline__ long long blockReduceLL(long long x, long long* lds) {
  #pragma unroll
  for (int off = 32; off; off >>= 1) x += __shfl_down(x, off, 64);
  int wv = threadIdx.x >> 6;
  __syncthreads();
  if ((threadIdx.x & 63) == 0) lds[wv] = x;
  __syncthreads();
  return lds[0] + lds[1] + lds[2] + lds[3];
}

// ---------- K1: per-(b,feature) mean/std(ddof=1) + normalize ----------
__global__ __launch_bounds__(256) void k_norm(const float* __restrict__ data,
                                              float* __restrict__ xnT) {
  __shared__ double lds[4];
  __shared__ float msd[2];
  const int blk = blockIdx.x;
  const int t = threadIdx.x;
  const float* src = data + (size_t)blk * NN;
  float* dst = xnT + (size_t)blk * NN;
  float v[8];
  double s = 0.0, s2 = 0.0;
  #pragma unroll
  for (int q = 0; q < 8; ++q) {
    v[q] = src[t + q * 256];
    double d = (double)v[q];
    s += d;
    s2 = fma(d, d, s2);
  }
  s  = blockReduceD(s, lds);
  s2 = blockReduceD(s2, lds);
  if (t == 0) {
    double mean = s * (1.0 / 2048.0);
    double var = (s2 - s * mean) / 2047.0;
    if (var < 0.0) var = 0.0;
    msd[0] = (float)mean;
    msd[1] = (float)sqrt(var);
  }
  __syncthreads();
  const float mean = msd[0];
  const float den = msd[1] + 1e-6f;
  #pragma unroll
  for (int q = 0; q < 8; ++q)
    dst[t + q * 256] = (v[q] - mean) / den;
}

// ---------- K2: sq[b][n] = sum_d Xn^2 (fp64) ----------
__global__ __launch_bounds__(256) void k_sq(const float* __restrict__ xnT,
                                            double* __restrict__ sq) {
  const int g = blockIdx.x * 256 + threadIdx.x;
  const int b = g >> 11, n = g & 2047;
  const float* X = xnT + (size_t)b * DDIM * NN + n;
  double s = 0.0;
  for (int d = 0; d < DDIM; ++d) {
    double x = (double)X[(size_t)d * NN];
    s = fma(x, x, s);
  }
  sq[g] = s;
}

// ---------- K3: 8-row distance tile; MODE 0: select + store dist,
//              MODE 1: select only, MODE 2: recompute + count (fallback) ----
// grid 2048 (b*256 + rowgroup), block 256
template<int MODE>
__global__ __launch_bounds__(256, 2) void k_dist(
    const float* __restrict__ xnT, const double* __restrict__ sq,
    float* __restrict__ kth, float* __restrict__ distOut,
    const float* __restrict__ adj, const float* __restrict__ Rf,
    float* __restrict__ samples, float* __restrict__ neigh,
    float* __restrict__ degree) {
  __shared__ double rowd[DDIM][ROWS];   // 8 KB
  __shared__ float dtile[ROWS][NN];     // 64 KB (used MODE<2)
  __shared__ long long ldsLL[4];
  const int b = blockIdx.x >> 8;
  const int i0 = (blockIdx.x & 255) * ROWS;
  const int t = threadIdx.x;
  const float* Xb = xnT + (size_t)b * DDIM * NN;

  // stage the 8 "query" rows (columns i0..i0+7 of Xb) as fp64
  #pragma unroll
  for (int q = 0; q < 4; ++q) {
    const int idx = t + q * 256;          // 0..1023
    const int d = idx >> 3, r = idx & 7;
    rowd[d][r] = (double)Xb[(size_t)d * NN + i0 + r];
  }
  __syncthreads();

  double acc[ROWS][8];
  #pragma unroll
  for (int r = 0; r < ROWS; ++r)
    #pragma unroll
    for (int q = 0; q < 8; ++q) acc[r][q] = 0.0;

  for (int d = 0; d < DDIM; ++d) {
    const float4* c4 = (const float4*)(Xb + ((size_t)d << 11)) + (t << 1);
    const float4 c0 = c4[0], c1 = c4[1];
    double cd[8];
    cd[0] = (double)c0.x; cd[1] = (double)c0.y;
    cd[2] = (double)c0.z; cd[3] = (double)c0.w;
    cd[4] = (double)c1.x; cd[5] = (double)c1.y;
    cd[6] = (double)c1.z; cd[7] = (double)c1.w;
    #pragma unroll
    for (int r = 0; r < ROWS; ++r) {
      const double rv = rowd[d][r];
      #pragma unroll
      for (int q = 0; q < 8; ++q) acc[r][q] = fma(rv, cd[q], acc[r][q]);
    }
  }

  const double* sqb = sq + (b << 11);
  const float R = (MODE == 2) ? Rf[b] : 0.0f;
  long long pk[ROWS];

  #pragma unroll
  for (int r = 0; r < ROWS; ++r) {
    const double sqi = sqb[i0 + r];
    float f8[8];
    #pragma unroll
    for (int q = 0; q < 8; ++q) {
      double d2 = (sqi + sqb[(t << 3) + q]) - 2.0 * acc[r][q];
      if (d2 < 0.0) d2 = 0.0;
      f8[q] = (float)sqrt(d2);     // identical rounding point in all modes
    }
    if (MODE < 2) {
      #pragma unroll
      for (int q = 0; q < 8; ++q) dtile[r][(t << 3) + q] = f8[q];
      if (MODE == 0) {
        float4* drow = (float4*)(distOut + ((size_t)((b << 11) + i0 + r) << 11)) + (t << 1);
        drow[0] = make_float4(f8[0], f8[1], f8[2], f8[3]);
        drow[1] = make_float4(f8[4], f8[5], f8[6], f8[7]);
      }
    } else {
      const float* arow = adj + (size_t)(i0 + r) * NN + (t << 3);
      int sN = 0, nN = 0, dc = 0;
      #pragma unroll
      for (int q = 0; q < 8; ++q) {
        const float a = arow[q];
        sN += (f8[q] < R) ? 1 : 0;
        nN += ((a != 0.0f) && (f8[q] != 0.0f) && (f8[q] < R)) ? 1 : 0;
        dc += (a != 0.0f) ? 1 : 0;
      }
      pk[r] = (long long)sN | ((long long)nN << 12) | ((long long)dc << 24);
    }
  }

  if (MODE < 2) {
    __syncthreads();
    // wave w owns rows 2w, 2w+1; 32 values per lane; shfl-only radix select
    const int w = t >> 6, l = t & 63;
    #pragma unroll
    for (int rr = 0; rr < 2; ++rr) {
      const int r = w * 2 + rr;
      unsigned u[32];
      #pragma unroll
      for (int k = 0; k < 32; ++k) u[k] = __float_as_uint(dtile[r][k * 64 + l]);
      unsigned pref = 0;
      int want = KSEL;
      for (int bit = 30; bit >= 0; --bit) {
        const unsigned ps = pref >> bit;
        int c = 0;
        #pragma unroll
        for (int k = 0; k < 32; ++k) c += ((u[k] >> bit) == ps) ? 1 : 0;
        #pragma unroll
        for (int off = 1; off < 64; off <<= 1) c += __shfl_xor(c, off, 64);
        if (want >= c) { want -= c; pref |= (1u << bit); }
      }
      if (l == 0) kth[(b << 11) + i0 + r] = __uint_as_float(pref);
    }
  } else {
    #pragma unroll
    for (int r = 0; r < ROWS; ++r) {
      const long long s = blockReduceLL(pk[r], ldsLL);
      if (t == 0) {
        const int g = (b << 11) + i0 + r;
        samples[g] = (float)(s & 0xFFF);
        neigh[g]   = (float)((s >> 12) & 0xFFF);
        if (b == 0) degree[i0 + r] = (float)((s >> 24) & 0xFFF);
      }
    }
  }
}

// ---------- K4/K6: mean of 2048 floats -> float ----------
__global__ __launch_bounds__(256) void k_mean2048(const float* __restrict__ in,
                                                  float* __restrict__ out) {
  __shared__ double lds[4];
  const int b = blockIdx.x, t = threadIdx.x;
  const float* p = in + (b << 11);
  double s = 0.0;
  #pragma unroll
  for (int q = 0; q < 8; ++q) s += (double)p[t + q * 256];
  s = blockReduceD(s, lds);
  if (t == 0) out[b] = (float)(s * (1.0 / 2048.0));
}

// ---------- K5: counts from stored distances ----------
// grid 16384 (b*2048+i), block 256
__global__ __launch_bounds__(256) void k_count_read(
    const float* __restrict__ dist, const float* __restrict__ adj,
    const float* __restrict__ Rf,
    float* __restrict__ samples, float* __restrict__ neigh,
    float* __restrict__ degree) {
  __shared__ long long ldsLL[4];
  const int b = blockIdx.x >> 11, i = blockIdx.x & 2047;
  const int t = threadIdx.x;
  const float R = Rf[b];
  const float4* drow = (const float4*)(dist + ((size_t)blockIdx.x << 11)) + (t << 1);
  const float4* arow4 = (const float4*)(adj + ((size_t)i << 11)) + (t << 1);
  const float4 d0 = drow[0], d1 = drow[1];
  const float4 a0 = arow4[0], a1 = arow4[1];
  float f[8] = {d0.x, d0.y, d0.z, d0.w, d1.x, d1.y, d1.z, d1.w};
  float a[8] = {a0.x, a0.y, a0.z, a0.w, a1.x, a1.y, a1.z, a1.w};
  int sN = 0, nN = 0, dc = 0;
  #pragma unroll
  for (int q = 0; q < 8; ++q) {
    sN += (f[q] < R) ? 1 : 0;
    nN += ((a[q] != 0.0f) && (f[q] != 0.0f) && (f[q] < R)) ? 1 : 0;
    dc += (a[q] != 0.0f) ? 1 : 0;
  }
  long long pkv = (long long)sN | ((long long)nN << 12) | ((long long)dc << 24);
  pkv = blockReduceLL(pkv, ldsLL);
  if (t == 0) {
    samples[blockIdx.x] = (float)(pkv & 0xFFF);
    neigh[blockIdx.x]   = (float)((pkv >> 12) & 0xFFF);
    if (b == 0) degree[i] = (float)((pkv >> 24) & 0xFFF);
  }
}

// ---------- K7a: total_score (exact fp32 op order as reference) ----------
__global__ __launch_bounds__(256) void k_score(const float* __restrict__ neigh,
                                               const float* __restrict__ samples,
                                               const float* __restrict__ degree,
                                               const float* __restrict__ mf,
                                               float* __restrict__ score) {
  const int g = blockIdx.x * 256 + threadIdx.x;
  const int b = g >> 11, i = g & 2047;
  const float sp = neigh[g] / degree[i];
  const float s = samples[g];
  const float tp = s / (s + mf[b]);
  score[g] = (2.0f - sp) - tp;
}

// ---------- K7b: stable rank + mask ----------
__global__ __launch_bounds__(256) void k_rank(const float* __restrict__ score,
                                              float* __restrict__ mask) {
  __shared__ float sc[NN];
  const int b = blockIdx.x >> 3, chunk = blockIdx.x & 7, t = threadIdx.x;
  const float* srow = score + (b << 11);
  #pragma unroll
  for (int q = 0; q < 8; ++q) sc[t + q * 256] = srow[t + q * 256];
  __syncthreads();
  const int i = chunk * 256 + t;
  const float si = sc[i];
  int less = 0, eqb = 0;
  for (int j = 0; j < NN; ++j) {
    const float sj = sc[j];
    less += (sj < si) ? 1 : 0;
    eqb += ((sj == si) && (j < i)) ? 1 : 0;
  }
  const int rank = less + eqb;
  mask[(b << 11) + i] = (rank < KEEP) ? 1.0f : 0.0f;
}

// ---------- K8: out = data * mask ----------
__global__ __launch_bounds__(256) void k_apply(const float* __restrict__ data,
                                               const float* __restrict__ mask,
                                               float* __restrict__ out) {
  const int g = blockIdx.x * 256 + threadIdx.x;
  const float4 d = ((const float4*)data)[g];
  const int idx = g << 2;
  const int b = idx >> 18;
  const int w = idx & 2047;
  const float4 mk = *(const float4*)(mask + (b << 11) + w);
  float4 o;
  o.x = d.x * mk.x; o.y = d.y * mk.y; o.z = d.z * mk.z; o.w = d.w * mk.w;
  ((float4*)out)[g] = o;
}

extern "C" void kernel_launch(void* const* d_in, const int* in_sizes, int n_in,
                              void* d_out, int out_size, void* d_ws, size_t ws_size,
                              hipStream_t stream) {
  (void)in_sizes; (void)n_in; (void)out_size;
  const float* data = (const float*)d_in[0];
  const float* adj  = (const float*)d_in[1];
  float* out = (float*)d_out;

  float* xnT   = out;             // staged in output, overwritten by k_apply
  float* score = out + 2097152;   // total_score output slot (8*2048)

  uint8_t* w = (uint8_t*)d_ws;
  double* sq      = (double*)(w);            // 131072 B
  float*  kth     = (float*)(w + 131072);    // 65536 B
  float*  Rf      = (float*)(w + 196608);    // 32 B
  float*  samples = (float*)(w + 196672);    // 65536 B
  float*  neigh   = (float*)(w + 262208);    // 65536 B
  float*  mf      = (float*)(w + 327744);    // 32 B
  float*  degree  = (float*)(w + 327808);    // 8192 B
  float*  mask    = (float*)(w + 336000);    // 65536 B
  float*  distM   = (float*)(w + 1048576);   // 134217728 B (if ws allows)

  const size_t distBytes = (size_t)BZ * NN * NN * sizeof(float);
  const bool haveWS = ws_size >= 1048576 + distBytes;

  k_norm<<<1024, 256, 0, stream>>>(data, xnT);
  k_sq  <<<64,   256, 0, stream>>>(xnT, sq);

  if (haveWS) {
    k_dist<0><<<2048, 256, 0, stream>>>(xnT, sq, kth, distM, adj, Rf,
                                        samples, neigh, degree);
    k_mean2048<<<8, 256, 0, stream>>>(kth, Rf);
    k_count_read<<<16384, 256, 0, stream>>>(distM, adj, Rf, samples, neigh, degree);
  } else {
    k_dist<1><<<2048, 256, 0, stream>>>(xnT, sq, kth, nullptr, adj, Rf,
                                        samples, neigh, degree);
    k_mean2048<<<8, 256, 0, stream>>>(kth, Rf);
    k_dist<2><<<2048, 256, 0, stream>>>(xnT, sq, kth, nullptr, adj, Rf,
                                        samples, neigh, degree);
  }

  k_mean2048<<<8, 256, 0, stream>>>(samples, mf);
  k_score<<<64, 256, 0, stream>>>(neigh, samples, degree, mf, score);
  k_rank <<<64, 256, 0, stream>>>(score, mask);
  k_apply<<<2048, 256, 0, stream>>>(data, mask, out);
}

// Round 3
// 371.662 us; speedup vs baseline: 3.3211x; 1.2490x over previous
//
#include <hip/hip_runtime.h>
#include <math.h>

#define BZ   8
#define DDIM 128
#define NN   2048
#define KSEL 30
#define KEEP 1024
#define ROWS 8

// ---------- block reductions (blockDim == 256) ----------
__device__ __forceinline__ double blockReduceD(double x, double* lds) {
  #pragma unroll
  for (int off = 32; off; off >>= 1) x += __shfl_down(x, off, 64);
  int wv = threadIdx.x >> 6;
  __syncthreads();
  if ((threadIdx.x & 63) == 0) lds[wv] = x;
  __syncthreads();
  return lds[0] + lds[1] + lds[2] + lds[3];
}

__device__ __forceinline__ long long blockReduceLL(long long x, long long* lds) {
  #pragma unroll
  for (int off = 32; off; off >>= 1) x += __shfl_down(x, off, 64);
  int wv = threadIdx.x >> 6;
  __syncthreads();
  if ((threadIdx.x & 63) == 0) lds[wv] = x;
  __syncthreads();
  return lds[0] + lds[1] + lds[2] + lds[3];
}

// ---------- K1: per-(b,feature) mean/std(ddof=1) + normalize ----------
__global__ __launch_bounds__(256) void k_norm(const float* __restrict__ data,
                                              float* __restrict__ xnT) {
  __shared__ double lds[4];
  __shared__ float msd[2];
  const int blk = blockIdx.x;
  const int t = threadIdx.x;
  const float* src = data + (size_t)blk * NN;
  float* dst = xnT + (size_t)blk * NN;
  float v[8];
  double s = 0.0, s2 = 0.0;
  #pragma unroll
  for (int q = 0; q < 8; ++q) {
    v[q] = src[t + q * 256];
    double d = (double)v[q];
    s += d;
    s2 = fma(d, d, s2);
  }
  s  = blockReduceD(s, lds);
  s2 = blockReduceD(s2, lds);
  if (t == 0) {
    double mean = s * (1.0 / 2048.0);
    double var = (s2 - s * mean) / 2047.0;
    if (var < 0.0) var = 0.0;
    msd[0] = (float)mean;
    msd[1] = (float)sqrt(var);
  }
  __syncthreads();
  const float mean = msd[0];
  const float den = msd[1] + 1e-6f;
  #pragma unroll
  for (int q = 0; q < 8; ++q)
    dst[t + q * 256] = (v[q] - mean) / den;
}

// ---------- K2: sq[b][n] = sum_d Xn^2 (fp64) ----------
__global__ __launch_bounds__(256) void k_sq(const float* __restrict__ xnT,
                                            double* __restrict__ sq) {
  const int g = blockIdx.x * 256 + threadIdx.x;
  const int b = g >> 11, n = g & 2047;
  const float* X = xnT + (size_t)b * DDIM * NN + n;
  double s = 0.0;
  for (int d = 0; d < DDIM; ++d) {
    double x = (double)X[(size_t)d * NN];
    s = fma(x, x, s);
  }
  sq[g] = s;
}

// ---------- K3 (fast path): fp64 distance GEMM, store full matrix ----------
// grid 2048 (rowgroup*8 + b  -> b = blk&7 pins batch to XCD), block 512
// thread t: 8 rows x cols [4t..4t+3]
__global__ __launch_bounds__(512, 4) void k_gemm(const float* __restrict__ xnT,
                                                 const double* __restrict__ sq,
                                                 float* __restrict__ distM) {
  __shared__ double rowd[DDIM][ROWS];   // 8 KB
  const int b = blockIdx.x & 7;
  const int i0 = (blockIdx.x >> 3) * ROWS;
  const int t = threadIdx.x;
  const float* Xb = xnT + (size_t)b * DDIM * NN;

  #pragma unroll
  for (int q = 0; q < 2; ++q) {
    const int idx = t + q * 512;          // 0..1023
    const int d = idx >> 3, r = idx & 7;
    rowd[d][r] = (double)Xb[(size_t)d * NN + i0 + r];
  }
  __syncthreads();

  double acc[ROWS][4];
  #pragma unroll
  for (int r = 0; r < ROWS; ++r)
    #pragma unroll
    for (int q = 0; q < 4; ++q) acc[r][q] = 0.0;

  for (int d = 0; d < DDIM; ++d) {
    const float4 c0 = *((const float4*)(Xb + ((size_t)d << 11)) + t);
    double cd[4];
    cd[0] = (double)c0.x; cd[1] = (double)c0.y;
    cd[2] = (double)c0.z; cd[3] = (double)c0.w;
    #pragma unroll
    for (int r = 0; r < ROWS; ++r) {
      const double rv = rowd[d][r];
      #pragma unroll
      for (int q = 0; q < 4; ++q) acc[r][q] = fma(rv, cd[q], acc[r][q]);
    }
  }

  const double* sqb = sq + (b << 11);
  #pragma unroll
  for (int r = 0; r < ROWS; ++r) {
    const double sqi = sqb[i0 + r];
    float f4[4];
    #pragma unroll
    for (int q = 0; q < 4; ++q) {
      double d2 = (sqi + sqb[(t << 2) + q]) - 2.0 * acc[r][q];
      if (d2 < 0.0) d2 = 0.0;
      f4[q] = (float)sqrt(d2);           // identical rounding point as before
    }
    float4* drow = (float4*)(distM + (((size_t)((b << 11) + i0 + r)) << 11));
    drow[t] = make_float4(f4[0], f4[1], f4[2], f4[3]);
  }
}

// ---------- K3b: wave-per-row radix select of K-th smallest ----------
// grid 4096, block 256 (4 waves, one row each)
__global__ __launch_bounds__(256) void k_sel(const float* __restrict__ dist,
                                             float* __restrict__ kth) {
  const int row = (blockIdx.x << 2) + (threadIdx.x >> 6);
  const int l = threadIdx.x & 63;
  const float4* r4 = (const float4*)(dist + ((size_t)row << 11));
  unsigned u[32];
  #pragma unroll
  for (int j = 0; j < 8; ++j) {
    const float4 f = r4[(j << 6) + l];   // coalesced 1 KB per instruction
    u[j * 4 + 0] = __float_as_uint(f.x);
    u[j * 4 + 1] = __float_as_uint(f.y);
    u[j * 4 + 2] = __float_as_uint(f.z);
    u[j * 4 + 3] = __float_as_uint(f.w);
  }
  unsigned pref = 0;
  int want = KSEL;
  for (int bit = 30; bit >= 0; --bit) {
    const unsigned ps = pref >> bit;
    int c = 0;
    #pragma unroll
    for (int k = 0; k < 32; ++k)
      c += (int)__popcll(__ballot((u[k] >> bit) == ps));
    if (want >= c) { want -= c; pref |= (1u << bit); }
  }
  if (l == 0) kth[row] = __uint_as_float(pref);
}

// ---------- K4/K6: mean of 2048 floats -> float ----------
__global__ __launch_bounds__(256) void k_mean2048(const float* __restrict__ in,
                                                  float* __restrict__ out) {
  __shared__ double lds[4];
  const int b = blockIdx.x, t = threadIdx.x;
  const float* p = in + (b << 11);
  double s = 0.0;
  #pragma unroll
  for (int q = 0; q < 8; ++q) s += (double)p[t + q * 256];
  s = blockReduceD(s, lds);
  if (t == 0) out[b] = (float)(s * (1.0 / 2048.0));
}

// ---------- K5: counts from stored distances (ballot/popc) ----------
// grid 16384 (b*2048+i), block 256
__global__ __launch_bounds__(256) void k_count_read(
    const float* __restrict__ dist, const float* __restrict__ adj,
    const float* __restrict__ Rf,
    float* __restrict__ samples, float* __restrict__ neigh,
    float* __restrict__ degree) {
  __shared__ int pS[4], pN[4], pD[4];
  const int b = blockIdx.x >> 11, i = blockIdx.x & 2047;
  const int t = threadIdx.x, w = t >> 6, l = t & 63;
  const float R = Rf[b];
  const float4* drow = (const float4*)(dist + ((size_t)blockIdx.x << 11)) + (t << 1);
  const float4* arow = (const float4*)(adj + ((size_t)i << 11)) + (t << 1);
  const float4 d0 = drow[0], d1 = drow[1];
  const float4 a0 = arow[0], a1 = arow[1];
  const float f[8] = {d0.x, d0.y, d0.z, d0.w, d1.x, d1.y, d1.z, d1.w};
  const float a[8] = {a0.x, a0.y, a0.z, a0.w, a1.x, a1.y, a1.z, a1.w};
  int sN = 0, nN = 0, dc = 0;
  #pragma unroll
  for (int q = 0; q < 8; ++q) {
    sN += (int)__popcll(__ballot(f[q] < R));
    nN += (int)__popcll(__ballot((a[q] != 0.0f) && (f[q] != 0.0f) && (f[q] < R)));
    dc += (int)__popcll(__ballot(a[q] != 0.0f));
  }
  if (l == 0) { pS[w] = sN; pN[w] = nN; pD[w] = dc; }
  __syncthreads();
  if (t == 0) {
    samples[blockIdx.x] = (float)(pS[0] + pS[1] + pS[2] + pS[3]);
    neigh[blockIdx.x]   = (float)(pN[0] + pN[1] + pN[2] + pN[3]);
    if (b == 0) degree[i] = (float)(pD[0] + pD[1] + pD[2] + pD[3]);
  }
}

// ---------- fallback (ws too small): round-2 fused kernel, MODE 1/2 ----------
template<int MODE>
__global__ __launch_bounds__(256, 2) void k_dist(
    const float* __restrict__ xnT, const double* __restrict__ sq,
    float* __restrict__ kth, float* __restrict__ distOut,
    const float* __restrict__ adj, const float* __restrict__ Rf,
    float* __restrict__ samples, float* __restrict__ neigh,
    float* __restrict__ degree) {
  __shared__ double rowd[DDIM][ROWS];
  __shared__ float dtile[ROWS][NN];
  __shared__ long long ldsLL[4];
  const int b = blockIdx.x >> 8;
  const int i0 = (blockIdx.x & 255) * ROWS;
  const int t = threadIdx.x;
  const float* Xb = xnT + (size_t)b * DDIM * NN;
  #pragma unroll
  for (int q = 0; q < 4; ++q) {
    const int idx = t + q * 256;
    const int d = idx >> 3, r = idx & 7;
    rowd[d][r] = (double)Xb[(size_t)d * NN + i0 + r];
  }
  __syncthreads();
  double acc[ROWS][8];
  #pragma unroll
  for (int r = 0; r < ROWS; ++r)
    #pragma unroll
    for (int q = 0; q < 8; ++q) acc[r][q] = 0.0;
  for (int d = 0; d < DDIM; ++d) {
    const float4* c4 = (const float4*)(Xb + ((size_t)d << 11)) + (t << 1);
    const float4 c0 = c4[0], c1 = c4[1];
    double cd[8];
    cd[0] = (double)c0.x; cd[1] = (double)c0.y;
    cd[2] = (double)c0.z; cd[3] = (double)c0.w;
    cd[4] = (double)c1.x; cd[5] = (double)c1.y;
    cd[6] = (double)c1.z; cd[7] = (double)c1.w;
    #pragma unroll
    for (int r = 0; r < ROWS; ++r) {
      const double rv = rowd[d][r];
      #pragma unroll
      for (int q = 0; q < 8; ++q) acc[r][q] = fma(rv, cd[q], acc[r][q]);
    }
  }
  const double* sqb = sq + (b << 11);
  const float R = (MODE == 2) ? Rf[b] : 0.0f;
  long long pk[ROWS];
  #pragma unroll
  for (int r = 0; r < ROWS; ++r) {
    const double sqi = sqb[i0 + r];
    float f8[8];
    #pragma unroll
    for (int q = 0; q < 8; ++q) {
      double d2 = (sqi + sqb[(t << 3) + q]) - 2.0 * acc[r][q];
      if (d2 < 0.0) d2 = 0.0;
      f8[q] = (float)sqrt(d2);
    }
    if (MODE < 2) {
      #pragma unroll
      for (int q = 0; q < 8; ++q) dtile[r][(t << 3) + q] = f8[q];
    } else {
      const float* arow = adj + (size_t)(i0 + r) * NN + (t << 3);
      int sN = 0, nN = 0, dc = 0;
      #pragma unroll
      for (int q = 0; q < 8; ++q) {
        const float a = arow[q];
        sN += (f8[q] < R) ? 1 : 0;
        nN += ((a != 0.0f) && (f8[q] != 0.0f) && (f8[q] < R)) ? 1 : 0;
        dc += (a != 0.0f) ? 1 : 0;
      }
      pk[r] = (long long)sN | ((long long)nN << 12) | ((long long)dc << 24);
    }
  }
  if (MODE < 2) {
    __syncthreads();
    const int w = t >> 6, l = t & 63;
    #pragma unroll
    for (int rr = 0; rr < 2; ++rr) {
      const int r = w * 2 + rr;
      unsigned u[32];
      #pragma unroll
      for (int k = 0; k < 32; ++k) u[k] = __float_as_uint(dtile[r][k * 64 + l]);
      unsigned pref = 0;
      int want = KSEL;
      for (int bit = 30; bit >= 0; --bit) {
        const unsigned ps = pref >> bit;
        int c = 0;
        #pragma unroll
        for (int k = 0; k < 32; ++k) c += ((u[k] >> bit) == ps) ? 1 : 0;
        #pragma unroll
        for (int off = 1; off < 64; off <<= 1) c += __shfl_xor(c, off, 64);
        if (want >= c) { want -= c; pref |= (1u << bit); }
      }
      if (l == 0) kth[(b << 11) + i0 + r] = __uint_as_float(pref);
    }
  } else {
    #pragma unroll
    for (int r = 0; r < ROWS; ++r) {
      const long long s = blockReduceLL(pk[r], ldsLL);
      if (t == 0) {
        const int g = (b << 11) + i0 + r;
        samples[g] = (float)(s & 0xFFF);
        neigh[g]   = (float)((s >> 12) & 0xFFF);
        if (b == 0) degree[i0 + r] = (float)((s >> 24) & 0xFFF);
      }
    }
  }
}

// ---------- K7a: total_score (exact fp32 op order as reference) ----------
__global__ __launch_bounds__(256) void k_score(const float* __restrict__ neigh,
                                               const float* __restrict__ samples,
                                               const float* __restrict__ degree,
                                               const float* __restrict__ mf,
                                               float* __restrict__ score) {
  const int g = blockIdx.x * 256 + threadIdx.x;
  const int b = g >> 11, i = g & 2047;
  const float sp = neigh[g] / degree[i];
  const float s = samples[g];
  const float tp = s / (s + mf[b]);
  score[g] = (2.0f - sp) - tp;
}

// ---------- K7b: stable rank + mask ----------
__global__ __launch_bounds__(256) void k_rank(const float* __restrict__ score,
                                              float* __restrict__ mask) {
  __shared__ float sc[NN];
  const int b = blockIdx.x >> 3, chunk = blockIdx.x & 7, t = threadIdx.x;
  const float* srow = score + (b << 11);
  #pragma unroll
  for (int q = 0; q < 8; ++q) sc[t + q * 256] = srow[t + q * 256];
  __syncthreads();
  const int i = chunk * 256 + t;
  const float si = sc[i];
  int less = 0, eqb = 0;
  for (int j = 0; j < NN; ++j) {
    const float sj = sc[j];
    less += (sj < si) ? 1 : 0;
    eqb += ((sj == si) && (j < i)) ? 1 : 0;
  }
  const int rank = less + eqb;
  mask[(b << 11) + i] = (rank < KEEP) ? 1.0f : 0.0f;
}

// ---------- K8: out = data * mask ----------
__global__ __launch_bounds__(256) void k_apply(const float* __restrict__ data,
                                               const float* __restrict__ mask,
                                               float* __restrict__ out) {
  const int g = blockIdx.x * 256 + threadIdx.x;
  const float4 d = ((const float4*)data)[g];
  const int idx = g << 2;
  const int b = idx >> 18;
  const int w = idx & 2047;
  const float4 mk = *(const float4*)(mask + (b << 11) + w);
  float4 o;
  o.x = d.x * mk.x; o.y = d.y * mk.y; o.z = d.z * mk.z; o.w = d.w * mk.w;
  ((float4*)out)[g] = o;
}

extern "C" void kernel_launch(void* const* d_in, const int* in_sizes, int n_in,
                              void* d_out, int out_size, void* d_ws, size_t ws_size,
                              hipStream_t stream) {
  (void)in_sizes; (void)n_in; (void)out_size;
  const float* data = (const float*)d_in[0];
  const float* adj  = (const float*)d_in[1];
  float* out = (float*)d_out;

  float* xnT   = out;             // staged in output, overwritten by k_apply
  float* score = out + 2097152;   // total_score output slot (8*2048)

  uint8_t* w = (uint8_t*)d_ws;
  double* sq      = (double*)(w);            // 131072 B
  float*  kth     = (float*)(w + 131072);    // 65536 B
  float*  Rf      = (float*)(w + 196608);    // 32 B
  float*  samples = (float*)(w + 196672);    // 65536 B
  float*  neigh   = (float*)(w + 262208);    // 65536 B
  float*  mf      = (float*)(w + 327744);    // 32 B
  float*  degree  = (float*)(w + 327808);    // 8192 B
  float*  mask    = (float*)(w + 336000);    // 65536 B
  float*  distM   = (float*)(w + 1048576);   // 134217728 B (if ws allows)

  const size_t distBytes = (size_t)BZ * NN * NN * sizeof(float);
  const bool haveWS = ws_size >= 1048576 + distBytes;

  k_norm<<<1024, 256, 0, stream>>>(data, xnT);
  k_sq  <<<64,   256, 0, stream>>>(xnT, sq);

  if (haveWS) {
    k_gemm<<<2048, 512, 0, stream>>>(xnT, sq, distM);
    k_sel <<<4096, 256, 0, stream>>>(distM, kth);
    k_mean2048<<<8, 256, 0, stream>>>(kth, Rf);
    k_count_read<<<16384, 256, 0, stream>>>(distM, adj, Rf, samples, neigh, degree);
  } else {
    k_dist<1><<<2048, 256, 0, stream>>>(xnT, sq, kth, nullptr, adj, Rf,
                                        samples, neigh, degree);
    k_mean2048<<<8, 256, 0, stream>>>(kth, Rf);
    k_dist<2><<<2048, 256, 0, stream>>>(xnT, sq, kth, nullptr, adj, Rf,
                                        samples, neigh, degree);
  }

  k_mean2048<<<8, 256, 0, stream>>>(samples, mf);
  k_score<<<64, 256, 0, stream>>>(neigh, samples, degree, mf, score);
  k_rank <<<64, 256, 0, stream>>>(score, mask);
  k_apply<<<2048, 256, 0, stream>>>(data, mask, out);
}

// Round 4
// 365.884 us; speedup vs baseline: 3.3735x; 1.0158x over previous
//
#include <hip/hip_runtime.h>
#include <math.h>

#define BZ   8
#define DDIM 128
#define NN   2048
#define KSEL 30
#define KEEP 1024
#define ROWS 8

// ---------- block reductions (blockDim == 256) ----------
__device__ __forceinline__ double blockReduceD(double x, double* lds) {
  #pragma unroll
  for (int off = 32; off; off >>= 1) x += __shfl_down(x, off, 64);
  int wv = threadIdx.x >> 6;
  __syncthreads();
  if ((threadIdx.x & 63) == 0) lds[wv] = x;
  __syncthreads();
  return lds[0] + lds[1] + lds[2] + lds[3];
}

__device__ __forceinline__ long long blockReduceLL(long long x, long long* lds) {
  #pragma unroll
  for (int off = 32; off; off >>= 1) x += __shfl_down(x, off, 64);
  int wv = threadIdx.x >> 6;
  __syncthreads();
  if ((threadIdx.x & 63) == 0) lds[wv] = x;
  __syncthreads();
  return lds[0] + lds[1] + lds[2] + lds[3];
}

// ---------- K1: per-(b,feature) mean/std(ddof=1) + normalize ----------
// DBL=0: write fp32 to dstF (fallback tiers); DBL=1: write widened fp64 to dstD
template<int DBL>
__global__ __launch_bounds__(256) void k_norm(const float* __restrict__ data,
                                              float* __restrict__ dstF,
                                              double* __restrict__ dstD) {
  __shared__ double lds[4];
  __shared__ float msd[2];
  const int blk = blockIdx.x;
  const int t = threadIdx.x;
  const float* src = data + (size_t)blk * NN;
  float v[8];
  double s = 0.0, s2 = 0.0;
  #pragma unroll
  for (int q = 0; q < 8; ++q) {
    v[q] = src[t + q * 256];
    double d = (double)v[q];
    s += d;
    s2 = fma(d, d, s2);
  }
  s  = blockReduceD(s, lds);
  s2 = blockReduceD(s2, lds);
  if (t == 0) {
    double mean = s * (1.0 / 2048.0);
    double var = (s2 - s * mean) / 2047.0;
    if (var < 0.0) var = 0.0;
    msd[0] = (float)mean;
    msd[1] = (float)sqrt(var);
  }
  __syncthreads();
  const float mean = msd[0];
  const float den = msd[1] + 1e-6f;
  #pragma unroll
  for (int q = 0; q < 8; ++q) {
    const float xn = (v[q] - mean) / den;       // fp32 rounding point (as before)
    if (DBL) dstD[(size_t)blk * NN + t + q * 256] = (double)xn;
    else     dstF[(size_t)blk * NN + t + q * 256] = xn;
  }
}

// ---------- K2: sq[b][n] = sum_d Xn^2 (fp64), from fp64 input ----------
__global__ __launch_bounds__(256) void k_sqD(const double* __restrict__ xnD,
                                             double* __restrict__ sq) {
  const int g = blockIdx.x * 256 + threadIdx.x;
  const int b = g >> 11, n = g & 2047;
  const double* X = xnD + (size_t)b * DDIM * NN + n;
  double s = 0.0;
  for (int d = 0; d < DDIM; ++d) {
    const double x = X[(size_t)d << 11];
    s = fma(x, x, s);
  }
  sq[g] = s;
}

// ---------- K2 (fallback): sq from fp32 input ----------
__global__ __launch_bounds__(256) void k_sq(const float* __restrict__ xnT,
                                            double* __restrict__ sq) {
  const int g = blockIdx.x * 256 + threadIdx.x;
  const int b = g >> 11, n = g & 2047;
  const float* X = xnT + (size_t)b * DDIM * NN + n;
  double s = 0.0;
  for (int d = 0; d < DDIM; ++d) {
    double x = (double)X[(size_t)d * NN];
    s = fma(x, x, s);
  }
  sq[g] = s;
}

// ---------- K3 (fast): symmetric fp64 distance GEMM, 16 rows/block ----------
// grid 1024: blk = kk*8 + b; kk->gi pairing swizzle for load balance.
// Block computes rows [i0,i0+16) x cols [i0,2048); stores [i][j] AND [j][i]
// (bitwise-identical by commutativity). Thread t owns cols i0+4t..i0+4t+3.
__global__ __launch_bounds__(512) void k_gemm_sym(const double* __restrict__ xnD,
                                                  const double* __restrict__ sq,
                                                  float* __restrict__ distM) {
  __shared__ double rowd[DDIM][16];   // 16 KB
  const int b = blockIdx.x & 7;
  const int kk = blockIdx.x >> 3;                 // 0..127
  const int gi = (kk < 64) ? kk : 191 - kk;       // heavy+light pairing
  const int i0 = gi << 4;
  const int t = threadIdx.x;
  const double* Xb = xnD + (size_t)b * DDIM * NN;

  #pragma unroll
  for (int q = 0; q < 4; ++q) {
    const int idx = (t << 2) + q;      // 0..2047
    const int d = idx >> 4, r = idx & 15;
    rowd[d][r] = Xb[((size_t)d << 11) + i0 + r];
  }
  __syncthreads();

  const int j = i0 + (t << 2);
  if (j >= NN) return;                 // no further barriers below

  double acc[16][4];
  #pragma unroll
  for (int r = 0; r < 16; ++r)
    #pragma unroll
    for (int q = 0; q < 4; ++q) acc[r][q] = 0.0;

  const double* colp = Xb + j;
  for (int d = 0; d < DDIM; ++d) {
    const double* cp = colp + ((size_t)d << 11);
    const double2 p0 = *(const double2*)cp;
    const double2 p1 = *(const double2*)(cp + 2);
    #pragma unroll
    for (int r = 0; r < 16; ++r) {
      const double rv = rowd[d][r];
      acc[r][0] = fma(rv, p0.x, acc[r][0]);
      acc[r][1] = fma(rv, p0.y, acc[r][1]);
      acc[r][2] = fma(rv, p1.x, acc[r][2]);
      acc[r][3] = fma(rv, p1.y, acc[r][3]);
    }
  }

  const double* sqb = sq + (b << 11);
  float f[16][4];
  #pragma unroll
  for (int r = 0; r < 16; ++r) {
    const double sqi = sqb[i0 + r];
    #pragma unroll
    for (int q = 0; q < 4; ++q) {
      double d2 = (sqi + sqb[j + q]) - 2.0 * acc[r][q];
      if (d2 < 0.0) d2 = 0.0;
      f[r][q] = (float)sqrt(d2);       // identical rounding point as before
    }
    *(float4*)(distM + (((size_t)(b << 11) + i0 + r) << 11) + j) =
        make_float4(f[r][0], f[r][1], f[r][2], f[r][3]);
  }
  #pragma unroll
  for (int q = 0; q < 4; ++q) {
    float* trow = distM + (((size_t)(b << 11) + j + q) << 11) + i0;
    #pragma unroll
    for (int g = 0; g < 4; ++g)
      *(float4*)(trow + (g << 2)) = make_float4(f[g * 4 + 0][q], f[g * 4 + 1][q],
                                                f[g * 4 + 2][q], f[g * 4 + 3][q]);
  }
}

// ---------- K3 (tier-2 fallback): round-3 non-symmetric GEMM ----------
__global__ __launch_bounds__(512, 4) void k_gemm(const float* __restrict__ xnT,
                                                 const double* __restrict__ sq,
                                                 float* __restrict__ distM) {
  __shared__ double rowd[DDIM][ROWS];
  const int b = blockIdx.x & 7;
  const int i0 = (blockIdx.x >> 3) * ROWS;
  const int t = threadIdx.x;
  const float* Xb = xnT + (size_t)b * DDIM * NN;
  #pragma unroll
  for (int q = 0; q < 2; ++q) {
    const int idx = t + q * 512;
    const int d = idx >> 3, r = idx & 7;
    rowd[d][r] = (double)Xb[(size_t)d * NN + i0 + r];
  }
  __syncthreads();
  double acc[ROWS][4];
  #pragma unroll
  for (int r = 0; r < ROWS; ++r)
    #pragma unroll
    for (int q = 0; q < 4; ++q) acc[r][q] = 0.0;
  for (int d = 0; d < DDIM; ++d) {
    const float4 c0 = *((const float4*)(Xb + ((size_t)d << 11)) + t);
    double cd[4];
    cd[0] = (double)c0.x; cd[1] = (double)c0.y;
    cd[2] = (double)c0.z; cd[3] = (double)c0.w;
    #pragma unroll
    for (int r = 0; r < ROWS; ++r) {
      const double rv = rowd[d][r];
      #pragma unroll
      for (int q = 0; q < 4; ++q) acc[r][q] = fma(rv, cd[q], acc[r][q]);
    }
  }
  const double* sqb = sq + (b << 11);
  #pragma unroll
  for (int r = 0; r < ROWS; ++r) {
    const double sqi = sqb[i0 + r];
    float f4[4];
    #pragma unroll
    for (int q = 0; q < 4; ++q) {
      double d2 = (sqi + sqb[(t << 2) + q]) - 2.0 * acc[r][q];
      if (d2 < 0.0) d2 = 0.0;
      f4[q] = (float)sqrt(d2);
    }
    float4* drow = (float4*)(distM + (((size_t)((b << 11) + i0 + r)) << 11));
    drow[t] = make_float4(f4[0], f4[1], f4[2], f4[3]);
  }
}

// ---------- K3b: wave-per-row radix select (count(u<mid) form) ----------
// grid 4096, block 256 (4 waves, one row each)
__global__ __launch_bounds__(256) void k_sel(const float* __restrict__ dist,
                                             float* __restrict__ kth) {
  const int row = (blockIdx.x << 2) + (threadIdx.x >> 6);
  const int l = threadIdx.x & 63;
  const float4* r4 = (const float4*)(dist + ((size_t)row << 11));
  unsigned u[32];
  #pragma unroll
  for (int jj = 0; jj < 8; ++jj) {
    const float4 fv = r4[(jj << 6) + l];
    u[jj * 4 + 0] = __float_as_uint(fv.x);
    u[jj * 4 + 1] = __float_as_uint(fv.y);
    u[jj * 4 + 2] = __float_as_uint(fv.z);
    u[jj * 4 + 3] = __float_as_uint(fv.w);
  }
  // V = element at sorted index KSEL. Invariant: V in [pref, pref+2^(bit+1)).
  // c = #(u < mid); c <= KSEL -> V >= mid.
  unsigned pref = 0;
  for (int bit = 30; bit >= 0; --bit) {
    const unsigned mid = pref | (1u << bit);
    int c = 0;
    #pragma unroll
    for (int k = 0; k < 32; ++k)
      c += (int)__popcll(__ballot(u[k] < mid));
    if (c <= KSEL) pref = mid;
  }
  if (l == 0) kth[row] = __uint_as_float(pref);
}

// ---------- K4: mean of 2048 floats -> float ----------
__global__ __launch_bounds__(256) void k_mean2048(const float* __restrict__ in,
                                                  float* __restrict__ out) {
  __shared__ double lds[4];
  const int b = blockIdx.x, t = threadIdx.x;
  const float* p = in + (b << 11);
  double s = 0.0;
  #pragma unroll
  for (int q = 0; q < 8; ++q) s += (double)p[t + q * 256];
  s = blockReduceD(s, lds);
  if (t == 0) out[b] = (float)(s * (1.0 / 2048.0));
}

// ---------- K5: counts from stored distances (ballot/popc) ----------
__global__ __launch_bounds__(256) void k_count_read(
    const float* __restrict__ dist, const float* __restrict__ adj,
    const float* __restrict__ Rf,
    float* __restrict__ samples, float* __restrict__ neigh,
    float* __restrict__ degree) {
  __shared__ int pS[4], pN[4], pD[4];
  const int b = blockIdx.x >> 11, i = blockIdx.x & 2047;
  const int t = threadIdx.x, w = t >> 6, l = t & 63;
  const float R = Rf[b];
  const float4* drow = (const float4*)(dist + ((size_t)blockIdx.x << 11)) + (t << 1);
  const float4* arow = (const float4*)(adj + ((size_t)i << 11)) + (t << 1);
  const float4 d0 = drow[0], d1 = drow[1];
  const float4 a0 = arow[0], a1 = arow[1];
  const float f[8] = {d0.x, d0.y, d0.z, d0.w, d1.x, d1.y, d1.z, d1.w};
  const float a[8] = {a0.x, a0.y, a0.z, a0.w, a1.x, a1.y, a1.z, a1.w};
  int sN = 0, nN = 0, dc = 0;
  #pragma unroll
  for (int q = 0; q < 8; ++q) {
    sN += (int)__popcll(__ballot(f[q] < R));
    nN += (int)__popcll(__ballot((a[q] != 0.0f) && (f[q] != 0.0f) && (f[q] < R)));
    dc += (int)__popcll(__ballot(a[q] != 0.0f));
  }
  if (l == 0) { pS[w] = sN; pN[w] = nN; pD[w] = dc; }
  __syncthreads();
  if (t == 0) {
    samples[blockIdx.x] = (float)(pS[0] + pS[1] + pS[2] + pS[3]);
    neigh[blockIdx.x]   = (float)(pN[0] + pN[1] + pN[2] + pN[3]);
    if (b == 0) degree[i] = (float)(pD[0] + pD[1] + pD[2] + pD[3]);
  }
}

// ---------- tier-3 fallback (tiny ws): round-2 fused kernel ----------
template<int MODE>
__global__ __launch_bounds__(256, 2) void k_dist(
    const float* __restrict__ xnT, const double* __restrict__ sq,
    float* __restrict__ kth, float* __restrict__ distOut,
    const float* __restrict__ adj, const float* __restrict__ Rf,
    float* __restrict__ samples, float* __restrict__ neigh,
    float* __restrict__ degree) {
  __shared__ double rowd[DDIM][ROWS];
  __shared__ float dtile[ROWS][NN];
  __shared__ long long ldsLL[4];
  const int b = blockIdx.x >> 8;
  const int i0 = (blockIdx.x & 255) * ROWS;
  const int t = threadIdx.x;
  const float* Xb = xnT + (size_t)b * DDIM * NN;
  #pragma unroll
  for (int q = 0; q < 4; ++q) {
    const int idx = t + q * 256;
    const int d = idx >> 3, r = idx & 7;
    rowd[d][r] = (double)Xb[(size_t)d * NN + i0 + r];
  }
  __syncthreads();
  double acc[ROWS][8];
  #pragma unroll
  for (int r = 0; r < ROWS; ++r)
    #pragma unroll
    for (int q = 0; q < 8; ++q) acc[r][q] = 0.0;
  for (int d = 0; d < DDIM; ++d) {
    const float4* c4 = (const float4*)(Xb + ((size_t)d << 11)) + (t << 1);
    const float4 c0 = c4[0], c1 = c4[1];
    double cd[8];
    cd[0] = (double)c0.x; cd[1] = (double)c0.y;
    cd[2] = (double)c0.z; cd[3] = (double)c0.w;
    cd[4] = (double)c1.x; cd[5] = (double)c1.y;
    cd[6] = (double)c1.z; cd[7] = (double)c1.w;
    #pragma unroll
    for (int r = 0; r < ROWS; ++r) {
      const double rv = rowd[d][r];
      #pragma unroll
      for (int q = 0; q < 8; ++q) acc[r][q] = fma(rv, cd[q], acc[r][q]);
    }
  }
  const double* sqb = sq + (b << 11);
  const float R = (MODE == 2) ? Rf[b] : 0.0f;
  long long pk[ROWS];
  #pragma unroll
  for (int r = 0; r < ROWS; ++r) {
    const double sqi = sqb[i0 + r];
    float f8[8];
    #pragma unroll
    for (int q = 0; q < 8; ++q) {
      double d2 = (sqi + sqb[(t << 3) + q]) - 2.0 * acc[r][q];
      if (d2 < 0.0) d2 = 0.0;
      f8[q] = (float)sqrt(d2);
    }
    if (MODE < 2) {
      #pragma unroll
      for (int q = 0; q < 8; ++q) dtile[r][(t << 3) + q] = f8[q];
    } else {
      const float* arow = adj + (size_t)(i0 + r) * NN + (t << 3);
      int sN = 0, nN = 0, dc = 0;
      #pragma unroll
      for (int q = 0; q < 8; ++q) {
        const float a = arow[q];
        sN += (f8[q] < R) ? 1 : 0;
        nN += ((a != 0.0f) && (f8[q] != 0.0f) && (f8[q] < R)) ? 1 : 0;
        dc += (a != 0.0f) ? 1 : 0;
      }
      pk[r] = (long long)sN | ((long long)nN << 12) | ((long long)dc << 24);
    }
  }
  if (MODE < 2) {
    __syncthreads();
    const int w = t >> 6, l = t & 63;
    #pragma unroll
    for (int rr = 0; rr < 2; ++rr) {
      const int r = w * 2 + rr;
      unsigned u[32];
      #pragma unroll
      for (int k = 0; k < 32; ++k) u[k] = __float_as_uint(dtile[r][k * 64 + l]);
      unsigned pref = 0;
      int want = KSEL;
      for (int bit = 30; bit >= 0; --bit) {
        const unsigned ps = pref >> bit;
        int c = 0;
        #pragma unroll
        for (int k = 0; k < 32; ++k) c += ((u[k] >> bit) == ps) ? 1 : 0;
        #pragma unroll
        for (int off = 1; off < 64; off <<= 1) c += __shfl_xor(c, off, 64);
        if (want >= c) { want -= c; pref |= (1u << bit); }
      }
      if (l == 0) kth[(b << 11) + i0 + r] = __uint_as_float(pref);
    }
  } else {
    #pragma unroll
    for (int r = 0; r < ROWS; ++r) {
      const long long s = blockReduceLL(pk[r], ldsLL);
      if (t == 0) {
        const int g = (b << 11) + i0 + r;
        samples[g] = (float)(s & 0xFFF);
        neigh[g]   = (float)((s >> 12) & 0xFFF);
        if (b == 0) degree[i0 + r] = (float)((s >> 24) & 0xFFF);
      }
    }
  }
}

// ---------- K6+K7a fused: mf = mean(samples) then total_score ----------
// grid 8 (one per batch), block 256
__global__ __launch_bounds__(256) void k_scoremean(const float* __restrict__ samples,
                                                   const float* __restrict__ neigh,
                                                   const float* __restrict__ degree,
                                                   float* __restrict__ score) {
  __shared__ double lds[4];
  __shared__ float mfs;
  const int b = blockIdx.x, t = threadIdx.x;
  const float* p = samples + (b << 11);
  double s = 0.0;
  #pragma unroll
  for (int q = 0; q < 8; ++q) s += (double)p[t + q * 256];
  s = blockReduceD(s, lds);
  if (t == 0) mfs = (float)(s * (1.0 / 2048.0));
  __syncthreads();
  const float mf = mfs;
  #pragma unroll
  for (int q = 0; q < 8; ++q) {
    const int i = t + q * 256;
    const int g = (b << 11) + i;
    const float sp = neigh[g] / degree[i];
    const float sv = samples[g];
    const float tp = sv / (sv + mf);
    score[g] = (2.0f - sp) - tp;
  }
}

// ---------- K7a (fallback path) ----------
__global__ __launch_bounds__(256) void k_score(const float* __restrict__ neigh,
                                               const float* __restrict__ samples,
                                               const float* __restrict__ degree,
                                               const float* __restrict__ mf,
                                               float* __restrict__ score) {
  const int g = blockIdx.x * 256 + threadIdx.x;
  const int b = g >> 11, i = g & 2047;
  const float sp = neigh[g] / degree[i];
  const float s = samples[g];
  const float tp = s / (s + mf[b]);
  score[g] = (2.0f - sp) - tp;
}

// ---------- K7b: stable rank + mask ----------
__global__ __launch_bounds__(256) void k_rank(const float* __restrict__ score,
                                              float* __restrict__ mask) {
  __shared__ float sc[NN];
  const int b = blockIdx.x >> 3, chunk = blockIdx.x & 7, t = threadIdx.x;
  const float* srow = score + (b << 11);
  #pragma unroll
  for (int q = 0; q < 8; ++q) sc[t + q * 256] = srow[t + q * 256];
  __syncthreads();
  const int i = chunk * 256 + t;
  const float si = sc[i];
  int less = 0, eqb = 0;
  for (int j = 0; j < NN; ++j) {
    const float sj = sc[j];
    less += (sj < si) ? 1 : 0;
    eqb += ((sj == si) && (j < i)) ? 1 : 0;
  }
  const int rank = less + eqb;
  mask[(b << 11) + i] = (rank < KEEP) ? 1.0f : 0.0f;
}

// ---------- K8: out = data * mask ----------
__global__ __launch_bounds__(256) void k_apply(const float* __restrict__ data,
                                               const float* __restrict__ mask,
                                               float* __restrict__ out) {
  const int g = blockIdx.x * 256 + threadIdx.x;
  const float4 d = ((const float4*)data)[g];
  const int idx = g << 2;
  const int b = idx >> 18;
  const int w = idx & 2047;
  const float4 mk = *(const float4*)(mask + (b << 11) + w);
  float4 o;
  o.x = d.x * mk.x; o.y = d.y * mk.y; o.z = d.z * mk.z; o.w = d.w * mk.w;
  ((float4*)out)[g] = o;
}

extern "C" void kernel_launch(void* const* d_in, const int* in_sizes, int n_in,
                              void* d_out, int out_size, void* d_ws, size_t ws_size,
                              hipStream_t stream) {
  (void)in_sizes; (void)n_in; (void)out_size;
  const float* data = (const float*)d_in[0];
  const float* adj  = (const float*)d_in[1];
  float* out = (float*)d_out;

  float* xnT   = out;             // fp32 Xn staged in output (fallback tiers)
  float* score = out + 2097152;   // total_score output slot (8*2048)

  uint8_t* w = (uint8_t*)d_ws;
  double* sq      = (double*)(w);            // 131072 B
  float*  kth     = (float*)(w + 131072);    // 65536 B
  float*  Rf      = (float*)(w + 196608);    // 32 B
  float*  samples = (float*)(w + 196672);    // 65536 B
  float*  neigh   = (float*)(w + 262208);    // 65536 B
  float*  mf      = (float*)(w + 327744);    // 32 B
  float*  degree  = (float*)(w + 327808);    // 8192 B
  float*  mask    = (float*)(w + 336000);    // 65536 B

  const size_t distBytes = (size_t)BZ * NN * NN * sizeof(float);  // 134217728
  const size_t xnDBytes  = (size_t)BZ * DDIM * NN * sizeof(double); // 16777216

  double* xnD    = (double*)(w + 1048576);
  float*  distM1 = (float*)(w + 1048576 + xnDBytes);  // tier-1 placement
  float*  distM2 = (float*)(w + 1048576);             // tier-2 placement

  const bool tier1 = ws_size >= 1048576 + xnDBytes + distBytes;
  const bool tier2 = ws_size >= 1048576 + distBytes;

  if (tier1) {
    k_norm<1><<<1024, 256, 0, stream>>>(data, nullptr, xnD);
    k_sqD<<<64, 256, 0, stream>>>(xnD, sq);
    k_gemm_sym<<<1024, 512, 0, stream>>>(xnD, sq, distM1);
    k_sel <<<4096, 256, 0, stream>>>(distM1, kth);
    k_mean2048<<<8, 256, 0, stream>>>(kth, Rf);
    k_count_read<<<16384, 256, 0, stream>>>(distM1, adj, Rf, samples, neigh, degree);
    k_scoremean<<<8, 256, 0, stream>>>(samples, neigh, degree, score);
  } else if (tier2) {
    k_norm<0><<<1024, 256, 0, stream>>>(data, xnT, nullptr);
    k_sq  <<<64, 256, 0, stream>>>(xnT, sq);
    k_gemm<<<2048, 512, 0, stream>>>(xnT, sq, distM2);
    k_sel <<<4096, 256, 0, stream>>>(distM2, kth);
    k_mean2048<<<8, 256, 0, stream>>>(kth, Rf);
    k_count_read<<<16384, 256, 0, stream>>>(distM2, adj, Rf, samples, neigh, degree);
    k_mean2048<<<8, 256, 0, stream>>>(samples, mf);
    k_score<<<64, 256, 0, stream>>>(neigh, samples, degree, mf, score);
  } else {
    k_norm<0><<<1024, 256, 0, stream>>>(data, xnT, nullptr);
    k_sq  <<<64, 256, 0, stream>>>(xnT, sq);
    k_dist<1><<<2048, 256, 0, stream>>>(xnT, sq, kth, nullptr, adj, Rf,
                                        samples, neigh, degree);
    k_mean2048<<<8, 256, 0, stream>>>(kth, Rf);
    k_dist<2><<<2048, 256, 0, stream>>>(xnT, sq, kth, nullptr, adj, Rf,
                                        samples, neigh, degree);
    k_mean2048<<<8, 256, 0, stream>>>(samples, mf);
    k_score<<<64, 256, 0, stream>>>(neigh, samples, degree, mf, score);
  }

  k_rank <<<64, 256, 0, stream>>>(score, mask);
  k_apply<<<2048, 256, 0, stream>>>(data, mask, out);
}

// Round 6
// 299.265 us; speedup vs baseline: 4.1245x; 1.2226x over previous
//
#include <hip/hip_runtime.h>
#include <math.h>

#define BZ   8
#define DDIM 128
#define NN   2048
#define KSEL 30
#define KEEP 1024
#define ROWS 8

// ---------- block reductions (blockDim == 256) ----------
__device__ __forceinline__ double blockReduceD(double x, double* lds) {
  #pragma unroll
  for (int off = 32; off; off >>= 1) x += __shfl_down(x, off, 64);
  int wv = threadIdx.x >> 6;
  __syncthreads();
  if ((threadIdx.x & 63) == 0) lds[wv] = x;
  __syncthreads();
  return lds[0] + lds[1] + lds[2] + lds[3];
}

__device__ __forceinline__ long long blockReduceLL(long long x, long long* lds) {
  #pragma unroll
  for (int off = 32; off; off >>= 1) x += __shfl_down(x, off, 64);
  int wv = threadIdx.x >> 6;
  __syncthreads();
  if ((threadIdx.x & 63) == 0) lds[wv] = x;
  __syncthreads();
  return lds[0] + lds[1] + lds[2] + lds[3];
}

// ---------- K1: per-(b,feature) mean/std(ddof=1) + normalize ----------
template<int DBL>
__global__ __launch_bounds__(256) void k_norm(const float* __restrict__ data,
                                              float* __restrict__ dstF,
                                              double* __restrict__ dstD) {
  __shared__ double lds[4];
  __shared__ float msd[2];
  const int blk = blockIdx.x;
  const int t = threadIdx.x;
  const float* src = data + (size_t)blk * NN;
  float v[8];
  double s = 0.0, s2 = 0.0;
  #pragma unroll
  for (int q = 0; q < 8; ++q) {
    v[q] = src[t + q * 256];
    double d = (double)v[q];
    s += d;
    s2 = fma(d, d, s2);
  }
  s  = blockReduceD(s, lds);
  s2 = blockReduceD(s2, lds);
  if (t == 0) {
    double mean = s * (1.0 / 2048.0);
    double var = (s2 - s * mean) / 2047.0;
    if (var < 0.0) var = 0.0;
    msd[0] = (float)mean;
    msd[1] = (float)sqrt(var);
  }
  __syncthreads();
  const float mean = msd[0];
  const float den = msd[1] + 1e-6f;
  #pragma unroll
  for (int q = 0; q < 8; ++q) {
    const float xn = (v[q] - mean) / den;       // fp32 rounding point (as before)
    if (DBL) dstD[(size_t)blk * NN + t + q * 256] = (double)xn;
    else     dstF[(size_t)blk * NN + t + q * 256] = xn;
  }
}

// ---------- K2: sq[b][n] = sum_d Xn^2 (fp64), from fp64 input ----------
__global__ __launch_bounds__(256) void k_sqD(const double* __restrict__ xnD,
                                             double* __restrict__ sq) {
  const int g = blockIdx.x * 256 + threadIdx.x;
  const int b = g >> 11, n = g & 2047;
  const double* X = xnD + (size_t)b * DDIM * NN + n;
  double s = 0.0;
  for (int d = 0; d < DDIM; ++d) {
    const double x = X[(size_t)d << 11];
    s = fma(x, x, s);
  }
  sq[g] = s;
}

// ---------- K2 (fallback): sq from fp32 input ----------
__global__ __launch_bounds__(256) void k_sq(const float* __restrict__ xnT,
                                            double* __restrict__ sq) {
  const int g = blockIdx.x * 256 + threadIdx.x;
  const int b = g >> 11, n = g & 2047;
  const float* X = xnT + (size_t)b * DDIM * NN + n;
  double s = 0.0;
  for (int d = 0; d < DDIM; ++d) {
    double x = (double)X[(size_t)d * NN];
    s = fma(x, x, s);
  }
  sq[g] = s;
}

// ---------- K3 (fast): cyclic-halved symmetric fp64 distance GEMM ----------
// Rowgroup g: rows [8g,8g+8), cols = 1024-wide cyclic window [8g, 8g+1024).
// Covers tile-pair separations m in [0,127]; m=128 (antipodal) is handled by
// k_gemm_anti below. Stores [i][j] and bitwise-identical mirror [j][i]
// (fp64 mul/add commute; same d-ascending fma chain; same (sqi+sqj) order).
__global__ __launch_bounds__(256, 3) void k_gemm_cyc(const double* __restrict__ xnD,
                                                     const double* __restrict__ sq,
                                                     float* __restrict__ distM) {
  __shared__ double rowd[DDIM][ROWS];   // 8 KB
  const int b = blockIdx.x & 7;
  const int g = blockIdx.x >> 3;        // 0..255
  const int i0 = g << 3;
  const int t = threadIdx.x;
  const double* Xb = xnD + (size_t)b * DDIM * NN;

  #pragma unroll
  for (int q = 0; q < 4; ++q) {
    const int idx = (t << 2) + q;       // 0..1023
    const int d = idx >> 3, r = idx & 7;
    rowd[d][r] = Xb[((size_t)d << 11) + i0 + r];
  }
  __syncthreads();

  const int c = (i0 + (t << 2)) & (NN - 1);   // first of this thread's 4 cols

  double acc[ROWS][4];
  #pragma unroll
  for (int r = 0; r < ROWS; ++r)
    #pragma unroll
    for (int q = 0; q < 4; ++q) acc[r][q] = 0.0;

  const double* colp = Xb + c;
  for (int d = 0; d < DDIM; ++d) {
    const double* cp = colp + ((size_t)d << 11);
    const double2 p0 = *(const double2*)cp;
    const double2 p1 = *(const double2*)(cp + 2);
    #pragma unroll
    for (int r = 0; r < ROWS; ++r) {
      const double rv = rowd[d][r];
      acc[r][0] = fma(rv, p0.x, acc[r][0]);
      acc[r][1] = fma(rv, p0.y, acc[r][1]);
      acc[r][2] = fma(rv, p1.x, acc[r][2]);
      acc[r][3] = fma(rv, p1.y, acc[r][3]);
    }
  }

  const double* sqb = sq + (b << 11);
  const double sqc0 = sqb[c], sqc1 = sqb[c + 1], sqc2 = sqb[c + 2], sqc3 = sqb[c + 3];
  float f[ROWS][4];
  #pragma unroll
  for (int r = 0; r < ROWS; ++r) {
    const double sqi = sqb[i0 + r];
    double d2;
    d2 = (sqi + sqc0) - 2.0 * acc[r][0]; if (d2 < 0.0) d2 = 0.0; f[r][0] = (float)sqrt(d2);
    d2 = (sqi + sqc1) - 2.0 * acc[r][1]; if (d2 < 0.0) d2 = 0.0; f[r][1] = (float)sqrt(d2);
    d2 = (sqi + sqc2) - 2.0 * acc[r][2]; if (d2 < 0.0) d2 = 0.0; f[r][2] = (float)sqrt(d2);
    d2 = (sqi + sqc3) - 2.0 * acc[r][3]; if (d2 < 0.0) d2 = 0.0; f[r][3] = (float)sqrt(d2);
    *(float4*)(distM + (((size_t)((b << 11) + i0 + r)) << 11) + c) =
        make_float4(f[r][0], f[r][1], f[r][2], f[r][3]);
  }
  // mirror store: rows c..c+3, cols i0..i0+7 (duplicates bitwise identical)
  #pragma unroll
  for (int q = 0; q < 4; ++q) {
    float* trow = distM + (((size_t)((b << 11) + c + q)) << 11) + i0;
    *(float4*)(trow)     = make_float4(f[0][q], f[1][q], f[2][q], f[3][q]);
    *(float4*)(trow + 4) = make_float4(f[4][q], f[5][q], f[6][q], f[7][q]);
  }
}

// ---------- K3a: antipodal tiles (separation 128) missed by the window ----
// grid 1024: blk = g*8 + b, g in [0,128). Rows [8g,8g+8) x cols [8g+1024,+8).
// Same fp64 fma chain / rounding points; stores [i][j] and mirror [j][i].
__global__ __launch_bounds__(64) void k_gemm_anti(const double* __restrict__ xnD,
                                                  const double* __restrict__ sq,
                                                  float* __restrict__ distM) {
  __shared__ double rowd[DDIM][8];   // 8 KB
  __shared__ double cold[DDIM][8];   // 8 KB
  const int b = blockIdx.x & 7;
  const int g = blockIdx.x >> 3;      // 0..127
  const int i0 = g << 3;
  const int j0 = i0 + 1024;
  const int t = threadIdx.x;          // 0..63
  const double* Xb = xnD + (size_t)b * DDIM * NN;
  #pragma unroll
  for (int q = 0; q < 16; ++q) {
    const int idx = (t << 4) + q;     // 0..1023
    const int d = idx >> 3, r = idx & 7;
    rowd[d][r] = Xb[((size_t)d << 11) + i0 + r];
    cold[d][r] = Xb[((size_t)d << 11) + j0 + r];
  }
  __syncthreads();
  const int r = t >> 3, q = t & 7;
  double acc = 0.0;
  for (int d = 0; d < DDIM; ++d)
    acc = fma(rowd[d][r], cold[d][q], acc);
  const double* sqb = sq + (b << 11);
  double d2 = (sqb[i0 + r] + sqb[j0 + q]) - 2.0 * acc;
  if (d2 < 0.0) d2 = 0.0;
  const float f = (float)sqrt(d2);
  distM[(((size_t)((b << 11) + i0 + r)) << 11) + j0 + q] = f;
  distM[(((size_t)((b << 11) + j0 + q)) << 11) + i0 + r] = f;
}

// ---------- K3 (tier-2 fallback): round-3 non-symmetric GEMM ----------
__global__ __launch_bounds__(512, 4) void k_gemm(const float* __restrict__ xnT,
                                                 const double* __restrict__ sq,
                                                 float* __restrict__ distM) {
  __shared__ double rowd[DDIM][ROWS];
  const int b = blockIdx.x & 7;
  const int i0 = (blockIdx.x >> 3) * ROWS;
  const int t = threadIdx.x;
  const float* Xb = xnT + (size_t)b * DDIM * NN;
  #pragma unroll
  for (int q = 0; q < 2; ++q) {
    const int idx = t + q * 512;
    const int d = idx >> 3, r = idx & 7;
    rowd[d][r] = (double)Xb[(size_t)d * NN + i0 + r];
  }
  __syncthreads();
  double acc[ROWS][4];
  #pragma unroll
  for (int r = 0; r < ROWS; ++r)
    #pragma unroll
    for (int q = 0; q < 4; ++q) acc[r][q] = 0.0;
  for (int d = 0; d < DDIM; ++d) {
    const float4 c0 = *((const float4*)(Xb + ((size_t)d << 11)) + t);
    double cd[4];
    cd[0] = (double)c0.x; cd[1] = (double)c0.y;
    cd[2] = (double)c0.z; cd[3] = (double)c0.w;
    #pragma unroll
    for (int r = 0; r < ROWS; ++r) {
      const double rv = rowd[d][r];
      #pragma unroll
      for (int q = 0; q < 4; ++q) acc[r][q] = fma(rv, cd[q], acc[r][q]);
    }
  }
  const double* sqb = sq + (b << 11);
  #pragma unroll
  for (int r = 0; r < ROWS; ++r) {
    const double sqi = sqb[i0 + r];
    float f4[4];
    #pragma unroll
    for (int q = 0; q < 4; ++q) {
      double d2 = (sqi + sqb[(t << 2) + q]) - 2.0 * acc[r][q];
      if (d2 < 0.0) d2 = 0.0;
      f4[q] = (float)sqrt(d2);
    }
    float4* drow = (float4*)(distM + (((size_t)((b << 11) + i0 + r)) << 11));
    drow[t] = make_float4(f4[0], f4[1], f4[2], f4[3]);
  }
}

// ---------- K3b: wave-per-row radix select (count(u<mid) form) ----------
__global__ __launch_bounds__(256) void k_sel(const float* __restrict__ dist,
                                             float* __restrict__ kth) {
  const int row = (blockIdx.x << 2) + (threadIdx.x >> 6);
  const int l = threadIdx.x & 63;
  const float4* r4 = (const float4*)(dist + ((size_t)row << 11));
  unsigned u[32];
  #pragma unroll
  for (int jj = 0; jj < 8; ++jj) {
    const float4 fv = r4[(jj << 6) + l];
    u[jj * 4 + 0] = __float_as_uint(fv.x);
    u[jj * 4 + 1] = __float_as_uint(fv.y);
    u[jj * 4 + 2] = __float_as_uint(fv.z);
    u[jj * 4 + 3] = __float_as_uint(fv.w);
  }
  unsigned pref = 0;
  for (int bit = 30; bit >= 0; --bit) {
    const unsigned mid = pref | (1u << bit);
    int c = 0;
    #pragma unroll
    for (int k = 0; k < 32; ++k)
      c += (int)__popcll(__ballot(u[k] < mid));
    if (c <= KSEL) pref = mid;
  }
  if (l == 0) kth[row] = __uint_as_float(pref);
}

// ---------- K4: mean of 2048 floats -> float ----------
__global__ __launch_bounds__(256) void k_mean2048(const float* __restrict__ in,
                                                  float* __restrict__ out) {
  __shared__ double lds[4];
  const int b = blockIdx.x, t = threadIdx.x;
  const float* p = in + (b << 11);
  double s = 0.0;
  #pragma unroll
  for (int q = 0; q < 8; ++q) s += (double)p[t + q * 256];
  s = blockReduceD(s, lds);
  if (t == 0) out[b] = (float)(s * (1.0 / 2048.0));
}

// ---------- K5: counts from stored distances (ballot/popc) ----------
__global__ __launch_bounds__(256) void k_count_read(
    const float* __restrict__ dist, const float* __restrict__ adj,
    const float* __restrict__ Rf,
    float* __restrict__ samples, float* __restrict__ neigh,
    float* __restrict__ degree) {
  __shared__ int pS[4], pN[4], pD[4];
  const int b = blockIdx.x >> 11, i = blockIdx.x & 2047;
  const int t = threadIdx.x, w = t >> 6, l = t & 63;
  const float R = Rf[b];
  const float4* drow = (const float4*)(dist + ((size_t)blockIdx.x << 11)) + (t << 1);
  const float4* arow = (const float4*)(adj + ((size_t)i << 11)) + (t << 1);
  const float4 d0 = drow[0], d1 = drow[1];
  const float4 a0 = arow[0], a1 = arow[1];
  const float f[8] = {d0.x, d0.y, d0.z, d0.w, d1.x, d1.y, d1.z, d1.w};
  const float a[8] = {a0.x, a0.y, a0.z, a0.w, a1.x, a1.y, a1.z, a1.w};
  int sN = 0, nN = 0, dc = 0;
  #pragma unroll
  for (int q = 0; q < 8; ++q) {
    sN += (int)__popcll(__ballot(f[q] < R));
    nN += (int)__popcll(__ballot((a[q] != 0.0f) && (f[q] != 0.0f) && (f[q] < R)));
    dc += (int)__popcll(__ballot(a[q] != 0.0f));
  }
  if (l == 0) { pS[w] = sN; pN[w] = nN; pD[w] = dc; }
  __syncthreads();
  if (t == 0) {
    samples[blockIdx.x] = (float)(pS[0] + pS[1] + pS[2] + pS[3]);
    neigh[blockIdx.x]   = (float)(pN[0] + pN[1] + pN[2] + pN[3]);
    if (b == 0) degree[i] = (float)(pD[0] + pD[1] + pD[2] + pD[3]);
  }
}

// ---------- tier-3 fallback (tiny ws): round-2 fused kernel ----------
template<int MODE>
__global__ __launch_bounds__(256, 2) void k_dist(
    const float* __restrict__ xnT, const double* __restrict__ sq,
    float* __restrict__ kth, float* __restrict__ distOut,
    const float* __restrict__ adj, const float* __restrict__ Rf,
    float* __restrict__ samples, float* __restrict__ neigh,
    float* __restrict__ degree) {
  __shared__ double rowd[DDIM][ROWS];
  __shared__ float dtile[ROWS][NN];
  __shared__ long long ldsLL[4];
  const int b = blockIdx.x >> 8;
  const int i0 = (blockIdx.x & 255) * ROWS;
  const int t = threadIdx.x;
  const float* Xb = xnT + (size_t)b * DDIM * NN;
  #pragma unroll
  for (int q = 0; q < 4; ++q) {
    const int idx = t + q * 256;
    const int d = idx >> 3, r = idx & 7;
    rowd[d][r] = (double)Xb[(size_t)d * NN + i0 + r];
  }
  __syncthreads();
  double acc[ROWS][8];
  #pragma unroll
  for (int r = 0; r < ROWS; ++r)
    #pragma unroll
    for (int q = 0; q < 8; ++q) acc[r][q] = 0.0;
  for (int d = 0; d < DDIM; ++d) {
    const float4* c4 = (const float4*)(Xb + ((size_t)d << 11)) + (t << 1);
    const float4 c0 = c4[0], c1 = c4[1];
    double cd[8];
    cd[0] = (double)c0.x; cd[1] = (double)c0.y;
    cd[2] = (double)c0.z; cd[3] = (double)c0.w;
    cd[4] = (double)c1.x; cd[5] = (double)c1.y;
    cd[6] = (double)c1.z; cd[7] = (double)c1.w;
    #pragma unroll
    for (int r = 0; r < ROWS; ++r) {
      const double rv = rowd[d][r];
      #pragma unroll
      for (int q = 0; q < 8; ++q) acc[r][q] = fma(rv, cd[q], acc[r][q]);
    }
  }
  const double* sqb = sq + (b << 11);
  const float R = (MODE == 2) ? Rf[b] : 0.0f;
  long long pk[ROWS];
  #pragma unroll
  for (int r = 0; r < ROWS; ++r) {
    const double sqi = sqb[i0 + r];
    float f8[8];
    #pragma unroll
    for (int q = 0; q < 8; ++q) {
      double d2 = (sqi + sqb[(t << 3) + q]) - 2.0 * acc[r][q];
      if (d2 < 0.0) d2 = 0.0;
      f8[q] = (float)sqrt(d2);
    }
    if (MODE < 2) {
      #pragma unroll
      for (int q = 0; q < 8; ++q) dtile[r][(t << 3) + q] = f8[q];
    } else {
      const float* arow = adj + (size_t)(i0 + r) * NN + (t << 3);
      int sN = 0, nN = 0, dc = 0;
      #pragma unroll
      for (int q = 0; q < 8; ++q) {
        const float a = arow[q];
        sN += (f8[q] < R) ? 1 : 0;
        nN += ((a != 0.0f) && (f8[q] != 0.0f) && (f8[q] < R)) ? 1 : 0;
        dc += (a != 0.0f) ? 1 : 0;
      }
      pk[r] = (long long)sN | ((long long)nN << 12) | ((long long)dc << 24);
    }
  }
  if (MODE < 2) {
    __syncthreads();
    const int w = t >> 6, l = t & 63;
    #pragma unroll
    for (int rr = 0; rr < 2; ++rr) {
      const int r = w * 2 + rr;
      unsigned u[32];
      #pragma unroll
      for (int k = 0; k < 32; ++k) u[k] = __float_as_uint(dtile[r][k * 64 + l]);
      unsigned pref = 0;
      int want = KSEL;
      for (int bit = 30; bit >= 0; --bit) {
        const unsigned ps = pref >> bit;
        int c = 0;
        #pragma unroll
        for (int k = 0; k < 32; ++k) c += ((u[k] >> bit) == ps) ? 1 : 0;
        #pragma unroll
        for (int off = 1; off < 64; off <<= 1) c += __shfl_xor(c, off, 64);
        if (want >= c) { want -= c; pref |= (1u << bit); }
      }
      if (l == 0) kth[(b << 11) + i0 + r] = __uint_as_float(pref);
    }
  } else {
    #pragma unroll
    for (int r = 0; r < ROWS; ++r) {
      const long long s = blockReduceLL(pk[r], ldsLL);
      if (t == 0) {
        const int g = (b << 11) + i0 + r;
        samples[g] = (float)(s & 0xFFF);
        neigh[g]   = (float)((s >> 12) & 0xFFF);
        if (b == 0) degree[i0 + r] = (float)((s >> 24) & 0xFFF);
      }
    }
  }
}

// ---------- K6+K7a fused: mf = mean(samples) then total_score ----------
__global__ __launch_bounds__(256) void k_scoremean(const float* __restrict__ samples,
                                                   const float* __restrict__ neigh,
                                                   const float* __restrict__ degree,
                                                   float* __restrict__ score) {
  __shared__ double lds[4];
  __shared__ float mfs;
  const int b = blockIdx.x, t = threadIdx.x;
  const float* p = samples + (b << 11);
  double s = 0.0;
  #pragma unroll
  for (int q = 0; q < 8; ++q) s += (double)p[t + q * 256];
  s = blockReduceD(s, lds);
  if (t == 0) mfs = (float)(s * (1.0 / 2048.0));
  __syncthreads();
  const float mf = mfs;
  #pragma unroll
  for (int q = 0; q < 8; ++q) {
    const int i = t + q * 256;
    const int g = (b << 11) + i;
    const float sp = neigh[g] / degree[i];
    const float sv = samples[g];
    const float tp = sv / (sv + mf);
    score[g] = (2.0f - sp) - tp;
  }
}

// ---------- K7a (fallback path) ----------
__global__ __launch_bounds__(256) void k_score(const float* __restrict__ neigh,
                                               const float* __restrict__ samples,
                                               const float* __restrict__ degree,
                                               const float* __restrict__ mf,
                                               float* __restrict__ score) {
  const int g = blockIdx.x * 256 + threadIdx.x;
  const int b = g >> 11, i = g & 2047;
  const float sp = neigh[g] / degree[i];
  const float s = samples[g];
  const float tp = s / (s + mf[b]);
  score[g] = (2.0f - sp) - tp;
}

// ---------- K7b: stable rank + mask ----------
__global__ __launch_bounds__(256) void k_rank(const float* __restrict__ score,
                                              float* __restrict__ mask) {
  __shared__ float sc[NN];
  const int b = blockIdx.x >> 3, chunk = blockIdx.x & 7, t = threadIdx.x;
  const float* srow = score + (b << 11);
  #pragma unroll
  for (int q = 0; q < 8; ++q) sc[t + q * 256] = srow[t + q * 256];
  __syncthreads();
  const int i = chunk * 256 + t;
  const float si = sc[i];
  int less = 0, eqb = 0;
  for (int j = 0; j < NN; ++j) {
    const float sj = sc[j];
    less += (sj < si) ? 1 : 0;
    eqb += ((sj == si) && (j < i)) ? 1 : 0;
  }
  const int rank = less + eqb;
  mask[(b << 11) + i] = (rank < KEEP) ? 1.0f : 0.0f;
}

// ---------- K8: out = data * mask ----------
__global__ __launch_bounds__(256) void k_apply(const float* __restrict__ data,
                                               const float* __restrict__ mask,
                                               float* __restrict__ out) {
  const int g = blockIdx.x * 256 + threadIdx.x;
  const float4 d = ((const float4*)data)[g];
  const int idx = g << 2;
  const int b = idx >> 18;
  const int w = idx & 2047;
  const float4 mk = *(const float4*)(mask + (b << 11) + w);
  float4 o;
  o.x = d.x * mk.x; o.y = d.y * mk.y; o.z = d.z * mk.z; o.w = d.w * mk.w;
  ((float4*)out)[g] = o;
}

extern "C" void kernel_launch(void* const* d_in, const int* in_sizes, int n_in,
                              void* d_out, int out_size, void* d_ws, size_t ws_size,
                              hipStream_t stream) {
  (void)in_sizes; (void)n_in; (void)out_size;
  const float* data = (const float*)d_in[0];
  const float* adj  = (const float*)d_in[1];
  float* out = (float*)d_out;

  float* xnT   = out;             // fp32 Xn staged in output (fallback tiers)
  float* score = out + 2097152;   // total_score output slot (8*2048)

  uint8_t* w = (uint8_t*)d_ws;
  double* sq      = (double*)(w);            // 131072 B
  float*  kth     = (float*)(w + 131072);    // 65536 B
  float*  Rf      = (float*)(w + 196608);    // 32 B
  float*  samples = (float*)(w + 196672);    // 65536 B
  float*  neigh   = (float*)(w + 262208);    // 65536 B
  float*  mf      = (float*)(w + 327744);    // 32 B
  float*  degree  = (float*)(w + 327808);    // 8192 B
  float*  mask    = (float*)(w + 336000);    // 65536 B

  const size_t distBytes = (size_t)BZ * NN * NN * sizeof(float);    // 134217728
  const size_t xnDBytes  = (size_t)BZ * DDIM * NN * sizeof(double); // 16777216

  double* xnD    = (double*)(w + 1048576);
  float*  distM1 = (float*)(w + 1048576 + xnDBytes);  // tier-1 placement
  float*  distM2 = (float*)(w + 1048576);             // tier-2 placement

  const bool tier1 = ws_size >= 1048576 + xnDBytes + distBytes;
  const bool tier2 = ws_size >= 1048576 + distBytes;

  if (tier1) {
    k_norm<1><<<1024, 256, 0, stream>>>(data, nullptr, xnD);
    k_sqD<<<64, 256, 0, stream>>>(xnD, sq);
    k_gemm_cyc <<<2048, 256, 0, stream>>>(xnD, sq, distM1);
    k_gemm_anti<<<1024,  64, 0, stream>>>(xnD, sq, distM1);
    k_sel <<<4096, 256, 0, stream>>>(distM1, kth);
    k_mean2048<<<8, 256, 0, stream>>>(kth, Rf);
    k_count_read<<<16384, 256, 0, stream>>>(distM1, adj, Rf, samples, neigh, degree);
    k_scoremean<<<8, 256, 0, stream>>>(samples, neigh, degree, score);
  } else if (tier2) {
    k_norm<0><<<1024, 256, 0, stream>>>(data, xnT, nullptr);
    k_sq  <<<64, 256, 0, stream>>>(xnT, sq);
    k_gemm<<<2048, 512, 0, stream>>>(xnT, sq, distM2);
    k_sel <<<4096, 256, 0, stream>>>(distM2, kth);
    k_mean2048<<<8, 256, 0, stream>>>(kth, Rf);
    k_count_read<<<16384, 256, 0, stream>>>(distM2, adj, Rf, samples, neigh, degree);
    k_mean2048<<<8, 256, 0, stream>>>(samples, mf);
    k_score<<<64, 256, 0, stream>>>(neigh, samples, degree, mf, score);
  } else {
    k_norm<0><<<1024, 256, 0, stream>>>(data, xnT, nullptr);
    k_sq  <<<64, 256, 0, stream>>>(xnT, sq);
    k_dist<1><<<2048, 256, 0, stream>>>(xnT, sq, kth, nullptr, adj, Rf,
                                        samples, neigh, degree);
    k_mean2048<<<8, 256, 0, stream>>>(kth, Rf);
    k_dist<2><<<2048, 256, 0, stream>>>(xnT, sq, kth, nullptr, adj, Rf,
                                        samples, neigh, degree);
    k_mean2048<<<8, 256, 0, stream>>>(samples, mf);
    k_score<<<64, 256, 0, stream>>>(neigh, samples, degree, mf, score);
  }

  k_rank <<<64, 256, 0, stream>>>(score, mask);
  k_apply<<<2048, 256, 0, stream>>>(data, mask, out);
}